// Round 9
// baseline (192.587 us; speedup 1.0000x reference)
//
#include <hip/hip_runtime.h>

// SSIM loss, separable 11-tap Gaussian. R9: R8 was co-bound LDS~54us/VALU~54us.
//  - 64x32 tile (halo amortized), grid 8x16x48 = 6144 blocks, ~44KB LDS.
//  - Col-pair f16 packing everywhere; v_pk_fma_f16 (2 MACs/instr) with f16
//    accumulators in both conv passes (no repack; R4 all-bf16 passed at 7.8e-3,
//    f16 is strictly more precise).
//  - Phase B: item = (row, col-oct): 8 outputs from 3+3 uint4 reads; shifted
//    pairs via funnel shift (alignbit); per-quantity loop caps registers.
//  - Phase C: item = (row-quad, col-quad): 16 outputs share 14 h-rows -> 70
//    b64 reads (2.7x per-px LDS cut vs R8).
//  - Interior blocks (65%) take an unguarded staging fast path.
// Reduction: per-block plain store + tiny reduce kernel (R6 lesson: no
// same-cacheline atomics).

typedef _Float16 h2 __attribute__((ext_vector_type(2)));

__device__ __forceinline__ unsigned h2u(h2 v) { return __builtin_bit_cast(unsigned, v); }
__device__ __forceinline__ h2 u2h(unsigned u) { return __builtin_bit_cast(h2, u); }
// shifted pair: (x[2p+1], x[2p+2]) from stored pairs p, p+1  -> v_alignbit
__device__ __forceinline__ unsigned shp(unsigned lo, unsigned hi) {
    return (lo >> 16) | (hi << 16);
}
__device__ __forceinline__ h2 pkfma(h2 a, h2 b, h2 c) {
    return __builtin_elementwise_fma(a, b, c);
}
__device__ __forceinline__ unsigned pk2(float a, float b) {
    return h2u((h2){(_Float16)a, (_Float16)b});
}

#define SXP 40   // sx/sy row stride in pairs (16B-mult, bank-staggered rows)
#define HPS 36   // h row stride in pairs (16B-mult)

__global__ __launch_bounds__(256) void ssim_main(
    const float* __restrict__ xg, const float* __restrict__ yg,
    const float* __restrict__ w2d, float* __restrict__ part)
{
    __shared__ __align__(16) unsigned sxp[42 * SXP];     // 6.7 KB x col-pairs
    __shared__ __align__(16) unsigned syp[42 * SXP];     // 6.7 KB y col-pairs
    __shared__ __align__(16) unsigned hq[5][42 * HPS];   // 30.2 KB h col-pairs
    __shared__ float gsf[11];
    __shared__ float wred[4];

    const int tid = threadIdx.x;

    // 1D kernel = row sums of the 2D window (window = outer(g,g), sum 1).
    if (tid < 11) {
        float s = 0.0f;
        #pragma unroll
        for (int j = 0; j < 11; ++j) s += w2d[tid * 11 + j];
        gsf[tid] = s;
    }

    const int x0 = blockIdx.x * 64 - 5;
    const int y0 = blockIdx.y * 32 - 5;
    const size_t zoff = (size_t)blockIdx.z * (512 * 512);
    const float* __restrict__ xp = xg + zoff;
    const float* __restrict__ yp = yg + zoff;

    // Phase A: stage 42 rows x 37 col-pairs (74 cols), zero-padded, f16 pairs.
    const bool interior = (x0 >= 0) & (x0 + 73 < 512) & (y0 >= 0) & (y0 + 41 < 512);
    if (interior) {
        for (int it = tid; it < 42 * 37; it += 256) {
            const int r = it / 37, p = it - r * 37;
            const int o = (y0 + r) * 512 + x0 + 2 * p;
            sxp[r * SXP + p] = pk2(xp[o], xp[o + 1]);
            syp[r * SXP + p] = pk2(yp[o], yp[o + 1]);
        }
    } else {
        for (int it = tid; it < 42 * 37; it += 256) {
            const int r = it / 37, p = it - r * 37;
            const int gr = y0 + r, gc = x0 + 2 * p;
            const bool rok = (unsigned)gr < 512u;
            const int o = gr * 512 + gc;
            float xv0 = 0.f, xv1 = 0.f, yv0 = 0.f, yv1 = 0.f;
            if (rok && (unsigned)gc < 512u)       { xv0 = xp[o];     yv0 = yp[o]; }
            if (rok && (unsigned)(gc + 1) < 512u) { xv1 = xp[o + 1]; yv1 = yp[o + 1]; }
            sxp[r * SXP + p] = pk2(xv0, xv1);
            syp[r * SXP + p] = pk2(yv0, yv1);
        }
    }
    __syncthreads();

    // Broadcast taps in f16, center-corrected so the f16 tap set sums to ~1.
    h2 g2[11];
    {
        _Float16 gh[11]; float ssum = 0.0f;
        #pragma unroll
        for (int k = 0; k < 11; ++k) {
            gh[k] = (_Float16)gsf[k];
            if (k != 5) ssum += (float)gh[k];
        }
        gh[5] = (_Float16)(1.0f - ssum);
        #pragma unroll
        for (int k = 0; k < 11; ++k) g2[k] = (h2){gh[k], gh[k]};
    }

    // Phase B: horizontal conv. Item = (row, col-oct): 8 outputs (4 pairs)
    // per quantity from stored pairs St[0..8] + shifted Sh[0..7].
    for (int it = tid; it < 42 * 8; it += 256) {
        const int r = it >> 3, co = it & 7;
        const int base = r * SXP + 4 * co;
        unsigned X[12], Y[12];
        *(uint4*)&X[0] = *(const uint4*)&sxp[base];
        *(uint4*)&X[4] = *(const uint4*)&sxp[base + 4];
        *(uint4*)&X[8] = *(const uint4*)&sxp[base + 8];
        *(uint4*)&Y[0] = *(const uint4*)&syp[base];
        *(uint4*)&Y[4] = *(const uint4*)&syp[base + 4];
        *(uint4*)&Y[8] = *(const uint4*)&syp[base + 8];

        const int ob = r * HPS + 4 * co;
        auto run_q = [&](const unsigned* St, int qi) {
            unsigned Sh[8];
            #pragma unroll
            for (int i = 0; i < 8; ++i) Sh[i] = shp(St[i], St[i + 1]);
            h2 a[4];
            #pragma unroll
            for (int j = 0; j < 4; ++j) a[j] = (h2){(_Float16)0.f, (_Float16)0.f};
            #pragma unroll
            for (int k = 0; k < 11; ++k) {
                #pragma unroll
                for (int j = 0; j < 4; ++j) {
                    const unsigned P = (k & 1) ? Sh[j + (k >> 1)] : St[j + (k >> 1)];
                    a[j] = pkfma(g2[k], u2h(P), a[j]);
                }
            }
            *(uint4*)&hq[qi][ob] = make_uint4(h2u(a[0]), h2u(a[1]), h2u(a[2]), h2u(a[3]));
        };

        run_q(X, 0);
        run_q(Y, 1);
        unsigned XX[9], YY[9], XY[9];
        #pragma unroll
        for (int i = 0; i < 9; ++i) {
            const h2 xv = u2h(X[i]), yv = u2h(Y[i]);
            XX[i] = h2u(xv * xv);     // v_pk_mul_f16
            YY[i] = h2u(yv * yv);
            XY[i] = h2u(xv * yv);
        }
        run_q(XX, 2);
        run_q(YY, 3);
        run_q(XY, 4);
    }
    __syncthreads();

    // Phase C: vertical conv + SSIM. Item = (row-quad rq, col-quad cqd):
    // 16 outputs (4 rows x 4 cols) share 14 h rows x 5 quantities (b64 reads).
    float lsum = 0.0f;
    if (tid < 128) {
        const int rq = tid >> 4, cqd = tid & 15;
        h2 A[5][4][2];
        #pragma unroll
        for (int q = 0; q < 5; ++q)
            #pragma unroll
            for (int e = 0; e < 4; ++e) {
                A[q][e][0] = (h2){(_Float16)0.f, (_Float16)0.f};
                A[q][e][1] = (h2){(_Float16)0.f, (_Float16)0.f};
            }
        #pragma unroll
        for (int j = 0; j < 14; ++j) {
            const int ro = (4 * rq + j) * HPS + 2 * cqd;
            #pragma unroll
            for (int q = 0; q < 5; ++q) {
                const uint2 V = *(const uint2*)&hq[q][ro];
                const h2 p0 = u2h(V.x), p1 = u2h(V.y);
                #pragma unroll
                for (int e = 0; e < 4; ++e) {
                    const int k = j - e;
                    if (k >= 0 && k <= 10) {
                        A[q][e][0] = pkfma(g2[k], p0, A[q][e][0]);
                        A[q][e][1] = pkfma(g2[k], p1, A[q][e][1]);
                    }
                }
            }
        }
        const float C1 = 1e-4f, C2 = 9e-4f;
        #pragma unroll
        for (int e = 0; e < 4; ++e) {
            #pragma unroll
            for (int pr = 0; pr < 2; ++pr) {
                #pragma unroll
                for (int el = 0; el < 2; ++el) {
                    const float mx  = (float)A[0][e][pr][el];
                    const float my  = (float)A[1][e][pr][el];
                    const float exx = (float)A[2][e][pr][el];
                    const float eyy = (float)A[3][e][pr][el];
                    const float exy = (float)A[4][e][pr][el];
                    const float mx2 = mx * mx, my2 = my * my, mxy = mx * my;
                    const float vx = exx - mx2, vy = eyy - my2, vxy = exy - mxy;
                    const float num = (2.0f * mxy + C1) * (2.0f * vxy + C2);
                    const float den = (mx2 + my2 + C1) * (vx + vy + C2) + 1e-12f;
                    lsum = fmaf(num, __builtin_amdgcn_rcpf(den), lsum);
                }
            }
        }
    }

    // Wave reduce -> cross-wave via LDS -> one plain store per block.
    #pragma unroll
    for (int off = 32; off > 0; off >>= 1)
        lsum += __shfl_down(lsum, off, 64);
    if ((tid & 63) == 0) wred[tid >> 6] = lsum;
    __syncthreads();
    if (tid == 0) {
        const int bid = (blockIdx.z * gridDim.y + blockIdx.y) * gridDim.x
                        + blockIdx.x;
        part[bid] = wred[0] + wred[1] + wred[2] + wred[3];
    }
}

__global__ __launch_bounds__(256) void ssim_reduce(
    const float* __restrict__ part, float* __restrict__ out,
    int n, float invN)
{
    __shared__ float wred[4];
    float s = 0.0f;
    for (int i = threadIdx.x; i < n; i += 256) s += part[i];
    #pragma unroll
    for (int off = 32; off > 0; off >>= 1)
        s += __shfl_down(s, off, 64);
    if ((threadIdx.x & 63) == 0) wred[threadIdx.x >> 6] = s;
    __syncthreads();
    if (threadIdx.x == 0)
        out[0] = 1.0f - (wred[0] + wred[1] + wred[2] + wred[3]) * invN;
}

extern "C" void kernel_launch(void* const* d_in, const int* in_sizes, int n_in,
                              void* d_out, int out_size, void* d_ws, size_t ws_size,
                              hipStream_t stream) {
    const float* x   = (const float*)d_in[0];
    const float* y   = (const float*)d_in[1];
    const float* w2d = (const float*)d_in[2];  // (3,1,11,11); channels identical
    float* out  = (float*)d_out;
    float* part = (float*)d_ws;                // 6144 floats = 24 KB

    const int H = 512, W = 512;
    const int total = in_sizes[0];              // 16*3*512*512
    const int Z = total / (H * W);              // 48

    dim3 grid(W / 64, H / 32, Z);               // 8 x 16 x 48 = 6144 blocks
    const int nblocks = (W / 64) * (H / 32) * Z;
    ssim_main<<<grid, 256, 0, stream>>>(x, y, w2d, part);

    const float invN = 1.0f / (float)total;
    ssim_reduce<<<1, 256, 0, stream>>>(part, out, nblocks, invN);
}

// Round 10
// 169.494 us; speedup vs baseline: 1.1362x; 1.1362x over previous
//
#include <hip/hip_runtime.h>

// SSIM loss, separable 11-tap Gaussian. R10 = R9's VALU cuts on R8's
// occupancy. Invariants from R2/R3/R9 regressions: LDS <= 40KB (>=4
// blocks/CU) and all 256 threads active in every phase.
//  - Stage x,y as ROW-PAIR f16 packs (elem0=even row, elem1=odd row).
//  - Phase B: horizontal pk_fma over columns on row-pairs -> h lands in
//    row-pair layout directly (no repack/unpack); squares via pk_mul.
//  - Phase C: tile 32x64 -> thread=(row-quad,col-pair)=256 threads; 4 output
//    rows share 7 row-pair reads x 2 cols x 5 q (35 b64 per 8 px, 2.6x cut
//    vs R8); vertical conv via fdot2 on (even,odd) tap pairs ge/go.
// Reduction: per-block plain store + reduce kernel (R6: no shared-line atomics).

typedef _Float16 h2 __attribute__((ext_vector_type(2)));
typedef __fp16 fp16x2 __attribute__((ext_vector_type(2)));

__device__ __forceinline__ unsigned h2u(h2 v) { return __builtin_bit_cast(unsigned, v); }
__device__ __forceinline__ unsigned h2u(fp16x2 v) { return __builtin_bit_cast(unsigned, v); }
__device__ __forceinline__ h2 u2h(unsigned u) { return __builtin_bit_cast(h2, u); }
__device__ __forceinline__ h2 pkfma(h2 a, h2 b, h2 c) {
    return __builtin_elementwise_fma(a, b, c);
}
__device__ __forceinline__ unsigned pk2(float a, float b) {
    return h2u(__builtin_amdgcn_cvt_pkrtz(a, b));
}
__device__ __forceinline__ float fdot2_(h2 a, h2 b, float c) {
#if defined(__has_builtin) && __has_builtin(__builtin_amdgcn_fdot2)
    return __builtin_amdgcn_fdot2(a, b, c, false);
#else
    return fmaf((float)a[1], (float)b[1], fmaf((float)a[0], (float)b[0], c));
#endif
}

#define SXW 44   // staged row-pair stride in words (42 cols + pad, mult of 4)
#define HPW 36   // h row-pair stride in words (32 cols + pad, mult of 4)

__global__ __launch_bounds__(256, 4) void ssim_main(
    const float* __restrict__ xg, const float* __restrict__ yg,
    const float* __restrict__ w2d, float* __restrict__ part)
{
    __shared__ __align__(16) unsigned sxrp[37 * SXW];   // 6.5 KB x row-pairs
    __shared__ __align__(16) unsigned syrp[37 * SXW];   // 6.5 KB y row-pairs
    __shared__ __align__(16) unsigned hq[5][37 * HPW];  // 26.6 KB h row-pairs
    __shared__ float gsf[11];
    __shared__ float wred[4];

    const int tid = threadIdx.x;

    // 1D kernel = row sums of the 2D window (window = outer(g,g), sum 1).
    if (tid < 11) {
        float s = 0.0f;
        #pragma unroll
        for (int j = 0; j < 11; ++j) s += w2d[tid * 11 + j];
        gsf[tid] = s;
    }

    // Tile: 32 cols x 64 rows. Staged: 42 cols x 74 rows (37 row-pairs).
    const int x0 = blockIdx.x * 32 - 5;
    const int y0 = blockIdx.y * 64 - 5;
    const size_t zoff = (size_t)blockIdx.z * (512 * 512);
    const float* __restrict__ xp = xg + zoff;
    const float* __restrict__ yp = yg + zoff;

    // Phase A: stage 37 row-pairs x 42 cols, zero-padded, row-pair packed.
    const bool interior = (x0 >= 0) & (x0 + 41 < 512) & (y0 >= 0) & (y0 + 73 < 512);
    if (interior) {
        for (int it = tid; it < 37 * 42; it += 256) {
            const int rp = it / 42, c = it - rp * 42;
            const int o = (y0 + 2 * rp) * 512 + x0 + c;
            sxrp[rp * SXW + c] = pk2(xp[o], xp[o + 512]);
            syrp[rp * SXW + c] = pk2(yp[o], yp[o + 512]);
        }
    } else {
        for (int it = tid; it < 37 * 42; it += 256) {
            const int rp = it / 42, c = it - rp * 42;
            const int gc = x0 + c;
            const int gr0 = y0 + 2 * rp;
            const bool cok = (unsigned)gc < 512u;
            float xv0 = 0.f, xv1 = 0.f, yv0 = 0.f, yv1 = 0.f;
            if (cok && (unsigned)gr0 < 512u) {
                const int o = gr0 * 512 + gc; xv0 = xp[o]; yv0 = yp[o];
            }
            if (cok && (unsigned)(gr0 + 1) < 512u) {
                const int o = (gr0 + 1) * 512 + gc; xv1 = xp[o]; yv1 = yp[o];
            }
            sxrp[rp * SXW + c] = pk2(xv0, xv1);
            syrp[rp * SXW + c] = pk2(yv0, yv1);
        }
    }
    __syncthreads();

    // Taps in f16 (center-corrected sum ~1): broadcast pairs for B,
    // even/odd phase pairs ge/go for C's row-pair dot2.
    h2 g2[11], ge[6], go[6];
    {
        _Float16 gh[12]; float ssum = 0.0f;
        #pragma unroll
        for (int k = 0; k < 11; ++k) {
            gh[k] = (_Float16)gsf[k];
            if (k != 5) ssum += (float)gh[k];
        }
        gh[5] = (_Float16)(1.0f - ssum);
        gh[11] = (_Float16)0.0f;
        #pragma unroll
        for (int k = 0; k < 11; ++k) g2[k] = (h2){gh[k], gh[k]};
        #pragma unroll
        for (int t = 0; t < 6; ++t) {
            ge[t] = (h2){gh[2 * t], gh[2 * t + 1]};                    // (g0,g1)..(g10,0)
            go[t] = (h2){(t == 0) ? (_Float16)0.f : gh[2 * t - 1],
                         gh[2 * t]};                                    // (0,g0)..(g9,g10)
        }
    }

    // Phase B: horizontal conv on row-pairs. Item = (rp, col-quad cq):
    // 4 output cols x 2 rows x 5 quantities from 16 staged words.
    for (int it = tid; it < 37 * 8; it += 256) {
        const int rp = it >> 3, cq = it & 7;
        const int base = rp * SXW + 4 * cq;
        unsigned X[16], Y[16];
        *(uint4*)&X[0]  = *(const uint4*)&sxrp[base];
        *(uint4*)&X[4]  = *(const uint4*)&sxrp[base + 4];
        *(uint4*)&X[8]  = *(const uint4*)&sxrp[base + 8];
        *(uint4*)&X[12] = *(const uint4*)&sxrp[base + 12];
        *(uint4*)&Y[0]  = *(const uint4*)&syrp[base];
        *(uint4*)&Y[4]  = *(const uint4*)&syrp[base + 4];
        *(uint4*)&Y[8]  = *(const uint4*)&syrp[base + 8];
        *(uint4*)&Y[12] = *(const uint4*)&syrp[base + 12];

        const int ob = rp * HPW + 4 * cq;
        auto conv_store = [&](const unsigned* S, int qi) {
            h2 a0 = (h2)0, a1 = (h2)0, a2 = (h2)0, a3 = (h2)0;
            #pragma unroll
            for (int k = 0; k < 11; ++k) {
                const h2 gk = g2[k];
                a0 = pkfma(gk, u2h(S[k]),     a0);
                a1 = pkfma(gk, u2h(S[k + 1]), a1);
                a2 = pkfma(gk, u2h(S[k + 2]), a2);
                a3 = pkfma(gk, u2h(S[k + 3]), a3);
            }
            *(uint4*)&hq[qi][ob] = make_uint4(h2u(a0), h2u(a1), h2u(a2), h2u(a3));
        };

        conv_store(X, 0);
        conv_store(Y, 1);
        unsigned T[14];
        #pragma unroll
        for (int i = 0; i < 14; ++i) { const h2 v = u2h(X[i]); T[i] = h2u(v * v); }
        conv_store(T, 2);
        #pragma unroll
        for (int i = 0; i < 14; ++i) { const h2 v = u2h(Y[i]); T[i] = h2u(v * v); }
        conv_store(T, 3);
        #pragma unroll
        for (int i = 0; i < 14; ++i) { T[i] = h2u(u2h(X[i]) * u2h(Y[i])); }
        conv_store(T, 4);
    }
    __syncthreads();

    // Phase C: vertical conv + SSIM. Thread = (row-quad rq, col-pair cp) —
    // exactly 256. Output rows 4rq..4rq+3 share h row-pairs 2rq..2rq+6.
    const int rq = tid >> 4, cp = tid & 15;
    float A_[5][4][2];
    #pragma unroll
    for (int q = 0; q < 5; ++q)
        #pragma unroll
        for (int e = 0; e < 4; ++e) { A_[q][e][0] = 0.f; A_[q][e][1] = 0.f; }

    #pragma unroll
    for (int q = 0; q < 5; ++q) {
        #pragma unroll
        for (int t = 0; t < 7; ++t) {
            const uint2 V = *(const uint2*)&hq[q][(2 * rq + t) * HPW + 2 * cp];
            const h2 p0 = u2h(V.x), p1 = u2h(V.y);
            if (t < 6) {
                A_[q][0][0] = fdot2_(ge[t], p0, A_[q][0][0]);
                A_[q][0][1] = fdot2_(ge[t], p1, A_[q][0][1]);
                A_[q][1][0] = fdot2_(go[t], p0, A_[q][1][0]);
                A_[q][1][1] = fdot2_(go[t], p1, A_[q][1][1]);
            }
            if (t >= 1) {
                A_[q][2][0] = fdot2_(ge[t - 1], p0, A_[q][2][0]);
                A_[q][2][1] = fdot2_(ge[t - 1], p1, A_[q][2][1]);
                A_[q][3][0] = fdot2_(go[t - 1], p0, A_[q][3][0]);
                A_[q][3][1] = fdot2_(go[t - 1], p1, A_[q][3][1]);
            }
        }
    }

    float lsum = 0.0f;
    const float C1 = 1e-4f, C2 = 9e-4f;
    #pragma unroll
    for (int e = 0; e < 4; ++e) {
        #pragma unroll
        for (int el = 0; el < 2; ++el) {
            const float mx  = A_[0][e][el], my  = A_[1][e][el];
            const float exx = A_[2][e][el], eyy = A_[3][e][el];
            const float exy = A_[4][e][el];
            const float mx2 = mx * mx, my2 = my * my, mxy = mx * my;
            const float vx = exx - mx2, vy = eyy - my2, vxy = exy - mxy;
            const float num = (2.0f * mxy + C1) * (2.0f * vxy + C2);
            const float den = (mx2 + my2 + C1) * (vx + vy + C2) + 1e-12f;
            lsum = fmaf(num, __builtin_amdgcn_rcpf(den), lsum);
        }
    }

    // Wave reduce -> cross-wave via LDS -> one plain store per block.
    #pragma unroll
    for (int off = 32; off > 0; off >>= 1)
        lsum += __shfl_down(lsum, off, 64);
    if ((tid & 63) == 0) wred[tid >> 6] = lsum;
    __syncthreads();
    if (tid == 0) {
        const int bid = (blockIdx.z * gridDim.y + blockIdx.y) * gridDim.x
                        + blockIdx.x;
        part[bid] = wred[0] + wred[1] + wred[2] + wred[3];
    }
}

__global__ __launch_bounds__(256) void ssim_reduce(
    const float* __restrict__ part, float* __restrict__ out,
    int n, float invN)
{
    __shared__ float wred[4];
    float s = 0.0f;
    for (int i = threadIdx.x; i < n; i += 256) s += part[i];
    #pragma unroll
    for (int off = 32; off > 0; off >>= 1)
        s += __shfl_down(s, off, 64);
    if ((threadIdx.x & 63) == 0) wred[threadIdx.x >> 6] = s;
    __syncthreads();
    if (threadIdx.x == 0)
        out[0] = 1.0f - (wred[0] + wred[1] + wred[2] + wred[3]) * invN;
}

extern "C" void kernel_launch(void* const* d_in, const int* in_sizes, int n_in,
                              void* d_out, int out_size, void* d_ws, size_t ws_size,
                              hipStream_t stream) {
    const float* x   = (const float*)d_in[0];
    const float* y   = (const float*)d_in[1];
    const float* w2d = (const float*)d_in[2];  // (3,1,11,11); channels identical
    float* out  = (float*)d_out;
    float* part = (float*)d_ws;                // 6144 floats = 24 KB

    const int H = 512, W = 512;
    const int total = in_sizes[0];              // 16*3*512*512
    const int Z = total / (H * W);              // 48

    dim3 grid(W / 32, H / 64, Z);               // 16 x 8 x 48 = 6144 blocks
    const int nblocks = (W / 32) * (H / 64) * Z;
    ssim_main<<<grid, 256, 0, stream>>>(x, y, w2d, part);

    const float invN = 1.0f / (float)total;
    ssim_reduce<<<1, 256, 0, stream>>>(part, out, nblocks, invN);
}